// Round 11
// baseline (990.916 us; speedup 1.0000x reference)
//
#include <hip/hip_runtime.h>

typedef __attribute__((ext_vector_type(4))) float f32x4;
typedef __attribute__((ext_vector_type(8))) short s16x8;

#define MFMA16(a, b, c) __builtin_amdgcn_mfma_f32_16x16x32_bf16((a), (b), (c), 0, 0, 0)

__device__ __forceinline__ float hsig(float x) {
    return fminf(fmaxf(0.2f * x + 0.5f, 0.0f), 1.0f);
}

__device__ __forceinline__ unsigned short bf16rne(float v) {
    unsigned u = __float_as_uint(v);
    u += 0x7FFFu + ((u >> 16) & 1u);
    return (unsigned short)(u >> 16);
}
__device__ __forceinline__ void split2(float v, unsigned short& h, unsigned short& l) {
    h = bf16rne(v);
    float hv = __uint_as_float((unsigned)h << 16);
    l = bf16rne(v - hv);
}

// ---- weight prep: reorder to MFMA B-fragment order ----
// Bw layout: [ks][ hi: nfrag(16) x lane(64) x 8 | lo: same ]  (16384 ushorts per ks)
template<int KHW, int CX, int NS>
__global__ __launch_bounds__(256)
void prep_w(const float* __restrict__ Kw, const float* __restrict__ Rw,
            unsigned short* __restrict__ Bw)
{
    int gid = blockIdx.x * 256 + threadIdx.x;
    if (gid >= NS * 1024) return;
    int lane  = gid & 63;
    int nfrag = (gid >> 6) & 15;
    int ks    = gid >> 10;
    int n  = nfrag * 16 + (lane & 15);
    int kl = (lane >> 4) * 8;
    constexpr int KX = KHW * CX;
    s16x8 vh, vl;
#pragma unroll
    for (int j = 0; j < 8; ++j) {
        int kg = ks * 32 + kl + j;
        float w = (kg < KX) ? Kw[(long)kg * 256 + n]
                            : Rw[(long)(kg - KX) * 256 + n];
        unsigned short h, l;
        split2(w, h, l);
        vh[j] = (short)h;
        vl[j] = (short)l;
    }
    unsigned short* o = Bw + (long)ks * 16384 + nfrag * 512 + lane * 8;
    *(s16x8*)o = vh;
    *(s16x8*)(o + 8192) = vl;
}

// ---- stage zero-padded tile as bf16 hi/lo planes, chunk-major [c/8][pixel][8] ----
template<int C, int TS, int PAD, int CST>
__device__ __forceinline__ void stage_split(const float* __restrict__ gp,
                                            unsigned short* __restrict__ hi_,
                                            unsigned short* __restrict__ lo_,
                                            int ty0, int tx0, int tid)
{
    constexpr int CH = C / 8;
    constexpr int NP = TS * TS;
    for (int i = tid; i < NP * CH; i += 512) {
        int ch = i % CH;
        int p  = i / CH;
        int py = p / TS, px = p % TS;
        int iy = ty0 + py - PAD, ix = tx0 + px - PAD;
        float v[8];
        if (iy >= 0 && iy < 64 && ix >= 0 && ix < 64) {
            const float* s = gp + ((long)(iy * 64 + ix)) * C + ch * 8;
            f32x4 a = *(const f32x4*)s;
            f32x4 b = *(const f32x4*)(s + 4);
#pragma unroll
            for (int j = 0; j < 4; ++j) { v[j] = a[j]; v[4 + j] = b[j]; }
        } else {
#pragma unroll
            for (int j = 0; j < 8; ++j) v[j] = 0.0f;
        }
        s16x8 vh, vl;
#pragma unroll
        for (int j = 0; j < 8; ++j) {
            unsigned short h, l;
            split2(v[j], h, l);
            vh[j] = (short)h;
            vl[j] = (short)l;
        }
        *(s16x8*)(hi_ + ch * CST + p * 8) = vh;
        *(s16x8*)(lo_ + ch * CST + p * 8) = vl;
    }
}

// ---- ConvLSTM step body: r3 wave map (80 arch + 32 acc regs) ----
// 8 waves; wave w owns ALL 64 pixels x 32 columns [32w, 32w+32), full K range.
template<int KW, int CX, int TS, int NS, int XS>
__device__ __forceinline__ void lstm_body(
    unsigned short* __restrict__ smem,
    const float* __restrict__ xin, long xbstride,
    const float* __restrict__ hin,
    const unsigned short* __restrict__ Bg,
    const float* __restrict__ bias,
    float* __restrict__ c_buf,
    float* __restrict__ h_out,
    float* __restrict__ y_out, long ybstride,
    int b)
{
    constexpr int PAD = KW / 2;
    constexpr int NP  = TS * TS;
    constexpr int CHX = CX / 8;
    constexpr int CST = NP * 8;              // chunk stride (ushorts)
    constexpr int XPLANE = CHX * CST;
    constexpr int HPLANE = 8 * CST;

    unsigned short* sxh = smem;
    unsigned short* sxl = sxh + XPLANE;
    unsigned short* shh = sxl + XPLANE;
    unsigned short* shl = shh + HPLANE;

    const int tid  = threadIdx.x;
    const int lane = tid & 63, wid = tid >> 6;
    const int ty0 = blockIdx.y * 8, tx0 = blockIdx.x * 8;

    // B fragment base: wave w owns nfrags {2w, 2w+1} = columns [32w, 32w+32)
    const unsigned short* bp = Bg + (2 * wid) * 512 + lane * 8;

    s16x8 Bh[2][2], Bl[2][2];
#define LOADB(BI, Q)                                             \
    {                                                            \
        const unsigned short* q_ = (Q);                          \
        Bh[BI][0] = *(const s16x8*)(q_);                         \
        Bh[BI][1] = *(const s16x8*)(q_ + 512);                   \
        Bl[BI][0] = *(const s16x8*)(q_ + 8192);                  \
        Bl[BI][1] = *(const s16x8*)(q_ + 8192 + 512);            \
    }

    LOADB(0, bp);             // ks 0, overlaps with staging

    stage_split<CX, TS, PAD, CST>(xin + (long)b * xbstride, sxh, sxl, ty0, tx0, tid);
    stage_split<64, TS, PAD, CST>(hin + (long)b * 4096 * 64, shh, shl, ty0, tx0, tid);
    __syncthreads();

    f32x4 acc[4][2];
#pragma unroll
    for (int mf = 0; mf < 4; ++mf)
#pragma unroll
        for (int nf = 0; nf < 2; ++nf)
#pragma unroll
            for (int q = 0; q < 4; ++q) acc[mf][nf][q] = 0.0f;

    // thread-const A offsets (ushort units). pixel p = mf*16 + (lane&15)
    const int pb  = lane & 15;
    const int kq  = (lane >> 4) * CST;
    const int av0 = (((pb      >> 3) * TS) + (pb      & 7)) * 8 + kq;
    const int av1 = ((((pb+16) >> 3) * TS) + ((pb+16) & 7)) * 8 + kq;
    const int av2 = ((((pb+32) >> 3) * TS) + ((pb+32) & 7)) * 8 + kq;
    const int av3 = ((((pb+48) >> 3) * TS) + ((pb+48) & 7)) * 8 + kq;

    s16x8 Ar[2][8];  // [buf][ mf0..3 hi | mf0..3 lo ]
#define LOADA(AI, KS)                                                    \
    {                                                                    \
        int ksv_ = (KS);                                                 \
        int tap_, cb8_;                                                  \
        const unsigned short *ph_, *pl_;                                 \
        if (ksv_ < XS) {                                                 \
            if (CX == 32) { tap_ = ksv_; cb8_ = 0; }                     \
            else { tap_ = ksv_ >> 1; cb8_ = (ksv_ & 1) * 4; }            \
            ph_ = sxh; pl_ = sxl;                                        \
        } else {                                                         \
            int kk_ = ksv_ - XS;                                         \
            tap_ = kk_ >> 1; cb8_ = (kk_ & 1) * 4;                       \
            ph_ = shh; pl_ = shl;                                        \
        }                                                                \
        int kh_ = tap_ / KW, kw_ = tap_ - kh_ * KW;                      \
        int so_ = cb8_ * CST + (kh_ * TS + kw_) * 8;                     \
        Ar[AI][0] = *(const s16x8*)(ph_ + so_ + av0);                    \
        Ar[AI][1] = *(const s16x8*)(ph_ + so_ + av1);                    \
        Ar[AI][2] = *(const s16x8*)(ph_ + so_ + av2);                    \
        Ar[AI][3] = *(const s16x8*)(ph_ + so_ + av3);                    \
        Ar[AI][4] = *(const s16x8*)(pl_ + so_ + av0);                    \
        Ar[AI][5] = *(const s16x8*)(pl_ + so_ + av1);                    \
        Ar[AI][6] = *(const s16x8*)(pl_ + so_ + av2);                    \
        Ar[AI][7] = *(const s16x8*)(pl_ + so_ + av3);                    \
    }

    // 3 passes: ah*bh, al*bh, ah*bl ; 8 independent acc chains
#define MM(AI, BI)                                                       \
    {                                                                    \
        __builtin_amdgcn_s_setprio(1);                                   \
        _Pragma("unroll")                                                \
        for (int mf = 0; mf < 4; ++mf) {                                 \
            acc[mf][0] = MFMA16(Ar[AI][mf], Bh[BI][0], acc[mf][0]);      \
            acc[mf][1] = MFMA16(Ar[AI][mf], Bh[BI][1], acc[mf][1]);      \
        }                                                                \
        _Pragma("unroll")                                                \
        for (int mf = 0; mf < 4; ++mf) {                                 \
            acc[mf][0] = MFMA16(Ar[AI][4+mf], Bh[BI][0], acc[mf][0]);    \
            acc[mf][1] = MFMA16(Ar[AI][4+mf], Bh[BI][1], acc[mf][1]);    \
        }                                                                \
        _Pragma("unroll")                                                \
        for (int mf = 0; mf < 4; ++mf) {                                 \
            acc[mf][0] = MFMA16(Ar[AI][mf], Bl[BI][0], acc[mf][0]);      \
            acc[mf][1] = MFMA16(Ar[AI][mf], Bl[BI][1], acc[mf][1]);      \
        }                                                                \
        __builtin_amdgcn_s_setprio(0);                                   \
    }

    LOADA(0, 0);

    const unsigned short* bq = bp;
    int ks = 0;
#pragma unroll 1
    for (; ks + 1 < NS; ks += 2, bq += 32768) {
        LOADB(1, bq + 16384);
        LOADA(1, ks + 1);
        MM(0, 0);
        if (ks + 2 < NS) {
            LOADB(0, bq + 32768);
            LOADA(0, ks + 2);
        }
        MM(1, 1);
    }
    if (ks < NS) MM(0, 0);   // odd-NS tail (buf0 holds ks)

    // ---- z exchange (2 rounds of 32 pixels, row stride 260) + gates ----
    __syncthreads();
    float* zl = (float*)smem;  // 32 x 260 f32 = 33.3 KB overlay
    const int f = tid & 63;
    const float bi = bias[f], bfr = bias[64 + f], bg = bias[128 + f], bo = bias[192 + f];

#define ZROUND(RR)                                                            \
    {                                                                         \
        _Pragma("unroll")                                                     \
        for (int mi = 0; mi < 2; ++mi)                                        \
        {                                                                     \
            _Pragma("unroll")                                                 \
            for (int nf = 0; nf < 2; ++nf)                                    \
            {                                                                 \
                _Pragma("unroll")                                             \
                for (int q = 0; q < 4; ++q) {                                 \
                    int pl_ = mi * 16 + (lane >> 4) * 4 + q;                  \
                    int c   = wid * 32 + nf * 16 + (lane & 15);               \
                    zl[pl_ * 260 + (c & 63) * 4 + (c >> 6)] =                 \
                        acc[2 * (RR) + mi][nf][q];                            \
                }                                                             \
            }                                                                 \
        }                                                                     \
        __syncthreads();                                                      \
        _Pragma("unroll")                                                     \
        for (int j = 0; j < 4; ++j) {                                         \
            int pl_ = (tid >> 6) + j * 8;                                     \
            int p   = (RR) * 32 + pl_;                                        \
            f32x4 z4 = *(const f32x4*)(zl + pl_ * 260 + f * 4);               \
            float zi = z4[0] + bi, zf = z4[1] + bfr;                          \
            float zg = z4[2] + bg, zo = z4[3] + bo;                           \
            int y = ty0 + (p >> 3), x = tx0 + (p & 7);                        \
            long o = ((long)((b * 64 + y) * 64 + x)) * 64 + f;                \
            float cv = c_buf[o];                                              \
            float cn = hsig(zf) * cv + hsig(zi) * tanhf(zg);                  \
            c_buf[o] = cn;                                                    \
            float hn = hsig(zo) * tanhf(cn);                                  \
            h_out[o] = hn;                                                    \
            y_out[(long)b * ybstride + ((long)(y * 64 + x)) * 64 + f] =       \
                fmaxf(hn, 0.0f);                                              \
        }                                                                     \
        __syncthreads();                                                      \
    }

    ZROUND(0)
    ZROUND(1)

#undef LOADB
#undef LOADA
#undef MM
#undef ZROUND
}

// ---- fused dual-layer launch: z<4 -> layer1 step t, z>=4 -> layer2 step t-1 ----
// __launch_bounds__(512, 4): the min-waves arg is the ONLY variable separating
// co-residency (r1/r7: 35-36% occ) from no-co-residency (r8-r10: 19-20%) --
// (512,2) licenses >128 total regs/wave (AGPRs excluded from the reported
// count), landing in the 2-3 waves/SIMD HW bin. Forcing the 128-total cap
// restores 4 waves/SIMD. Body needs 80 arch + 32 acc = 112 <= 128: no spill.
__global__ __launch_bounds__(512, 4)
void lstm_fused(
    const float* __restrict__ x1, const float* __restrict__ h1in,
    const unsigned short* __restrict__ B1g, const float* __restrict__ bias1,
    float* __restrict__ c1, float* __restrict__ h1out, float* __restrict__ y1out,
    const float* __restrict__ x2, const float* __restrict__ h2in,
    const unsigned short* __restrict__ B2g, const float* __restrict__ bias2,
    float* __restrict__ c2, float* __restrict__ h2out, float* __restrict__ y2out,
    int mode)
{
    __shared__ __align__(16) unsigned short smem[27648];  // 55296 B
    const int z = blockIdx.z;
    const int b = z & 3;
    const bool doL2 = (mode == 1) || (z >= 4);
    if (!doL2) {
        lstm_body<5, 32, 12, 75, 25>(smem, x1, (long)8 * 4096 * 32, h1in,
                                     B1g, bias1, c1, h1out,
                                     y1out, (long)8 * 4096 * 64, b);
    } else {
        lstm_body<3, 64, 10, 36, 18>(smem, x2, (long)8 * 4096 * 64, h2in,
                                     B2g, bias2, c2, h2out,
                                     y2out, (long)8 * 4096 * 64, b);
    }
}

extern "C" void kernel_launch(void* const* d_in, const int* in_sizes, int n_in,
                              void* d_out, int out_size, void* d_ws, size_t ws_size,
                              hipStream_t stream)
{
    const float* x  = (const float*)d_in[0];
    const float* K1 = (const float*)d_in[1];
    const float* R1 = (const float*)d_in[2];
    const float* b1 = (const float*)d_in[3];
    const float* K2 = (const float*)d_in[4];
    const float* R2 = (const float*)d_in[5];
    const float* b2 = (const float*)d_in[6];
    float* out = (float*)d_out;

    const long HW   = 4096;
    const long SZ_S = HW * 64 * 4;      // 1,048,576 floats per [B,H,W,64]
    const long SZ_Y = SZ_S * 8;

    float* ws  = (float*)d_ws;
    float* y1  = ws;                    // 8,388,608 f32 ([B][T][HW][64])
    float* h1a = y1 + SZ_Y;
    float* h1b = h1a + SZ_S;
    float* h2a = h1b + SZ_S;
    float* h2b = h2a + SZ_S;
    float* c1  = h2b + SZ_S;
    float* c2  = c1 + SZ_S;
    unsigned short* B1 = (unsigned short*)(c2 + SZ_S);   // 75*16384 ushorts
    unsigned short* B2 = B1 + (long)75 * 16384;          // 36*16384 ushorts

    // weight prep
    prep_w<25, 32, 75><<<300, 256, 0, stream>>>(K1, R1, B1);
    prep_w<9,  64, 36><<<144, 256, 0, stream>>>(K2, R2, B2);

    hipMemsetAsync(h1a, 0, (size_t)SZ_S * sizeof(float), stream);
    hipMemsetAsync(c1,  0, (size_t)SZ_S * sizeof(float), stream);
    hipMemsetAsync(h2a, 0, (size_t)SZ_S * sizeof(float), stream);
    hipMemsetAsync(c2,  0, (size_t)SZ_S * sizeof(float), stream);

    float* hp1 = h1a; float* hn1 = h1b;
    float* hp2 = h2a; float* hn2 = h2b;

    for (int t = 0; t <= 8; ++t) {
        const int mode = (t == 0) ? 0 : (t == 8) ? 1 : 2;
        const int t1  = (t <= 7) ? t : 7;       // L1 timestep (unused at t=8)
        const int tm1 = (t >= 1) ? t - 1 : 0;   // L2 timestep (unused at t=0)
        dim3 grid(8, 8, mode == 2 ? 8 : 4);
        lstm_fused<<<grid, 512, 0, stream>>>(
            x  + (long)t1 * HW * 32,  hp1, B1, b1, c1, hn1,
            y1 + (long)t1 * HW * 64,
            y1 + (long)tm1 * HW * 64, hp2, B2, b2, c2, hn2,
            out + (long)tm1 * HW * 64,
            mode);
        if (mode != 1) { float* tmp = hp1; hp1 = hn1; hn1 = tmp; }
        if (mode != 0) { float* tmp = hp2; hp2 = hn2; hn2 = tmp; }
    }
}

// Round 12
// 602.229 us; speedup vs baseline: 1.6454x; 1.6454x over previous
//
#include <hip/hip_runtime.h>

typedef __attribute__((ext_vector_type(4))) float f32x4;
typedef __attribute__((ext_vector_type(8))) short s16x8;

#define MFMA16(a, b, c) __builtin_amdgcn_mfma_f32_16x16x32_bf16((a), (b), (c), 0, 0, 0)

__device__ __forceinline__ float hsig(float x) {
    return fminf(fmaxf(0.2f * x + 0.5f, 0.0f), 1.0f);
}

__device__ __forceinline__ unsigned short bf16rne(float v) {
    unsigned u = __float_as_uint(v);
    u += 0x7FFFu + ((u >> 16) & 1u);
    return (unsigned short)(u >> 16);
}
__device__ __forceinline__ void split2(float v, unsigned short& h, unsigned short& l) {
    h = bf16rne(v);
    float hv = __uint_as_float((unsigned)h << 16);
    l = bf16rne(v - hv);
}

// ---- weight prep: reorder to MFMA B-fragment order ----
// Bw layout: [ks][ hi: nfrag(16) x lane(64) x 8 | lo: same ]  (16384 ushorts per ks)
template<int KHW, int CX, int NS>
__global__ __launch_bounds__(256)
void prep_w(const float* __restrict__ Kw, const float* __restrict__ Rw,
            unsigned short* __restrict__ Bw)
{
    int gid = blockIdx.x * 256 + threadIdx.x;
    if (gid >= NS * 1024) return;
    int lane  = gid & 63;
    int nfrag = (gid >> 6) & 15;
    int ks    = gid >> 10;
    int n  = nfrag * 16 + (lane & 15);
    int kl = (lane >> 4) * 8;
    constexpr int KX = KHW * CX;
    s16x8 vh, vl;
#pragma unroll
    for (int j = 0; j < 8; ++j) {
        int kg = ks * 32 + kl + j;
        float w = (kg < KX) ? Kw[(long)kg * 256 + n]
                            : Rw[(long)(kg - KX) * 256 + n];
        unsigned short h, l;
        split2(w, h, l);
        vh[j] = (short)h;
        vl[j] = (short)l;
    }
    unsigned short* o = Bw + (long)ks * 16384 + nfrag * 512 + lane * 8;
    *(s16x8*)o = vh;
    *(s16x8*)(o + 8192) = vl;
}

// ---- stage zero-padded tile as bf16 hi/lo planes, chunk-major [c/8][pixel][8] ----
template<int C, int TS, int PAD, int CST>
__device__ __forceinline__ void stage_split(const float* __restrict__ gp,
                                            unsigned short* __restrict__ hi_,
                                            unsigned short* __restrict__ lo_,
                                            int ty0, int tx0, int tid)
{
    constexpr int CH = C / 8;
    constexpr int NP = TS * TS;
    for (int i = tid; i < NP * CH; i += 512) {
        int ch = i % CH;
        int p  = i / CH;
        int py = p / TS, px = p % TS;
        int iy = ty0 + py - PAD, ix = tx0 + px - PAD;
        float v[8];
        if (iy >= 0 && iy < 64 && ix >= 0 && ix < 64) {
            const float* s = gp + ((long)(iy * 64 + ix)) * C + ch * 8;
            f32x4 a = *(const f32x4*)s;
            f32x4 b = *(const f32x4*)(s + 4);
#pragma unroll
            for (int j = 0; j < 4; ++j) { v[j] = a[j]; v[4 + j] = b[j]; }
        } else {
#pragma unroll
            for (int j = 0; j < 8; ++j) v[j] = 0.0f;
        }
        s16x8 vh, vl;
#pragma unroll
        for (int j = 0; j < 8; ++j) {
            unsigned short h, l;
            split2(v[j], h, l);
            vh[j] = (short)h;
            vl[j] = (short)l;
        }
        *(s16x8*)(hi_ + ch * CST + p * 8) = vh;
        *(s16x8*)(lo_ + ch * CST + p * 8) = vl;
    }
}

// ---- ConvLSTM step body: r3 wave map, compile-time-structured k-loop ----
// 8 waves; wave w owns ALL 64 pixels x 32 columns [32w, 32w+32), full K range.
// The k-loop is restructured as nested tap loops (x-phase, h-phase) with the
// inner 5-10 k-steps fully unrolled: all LDS offsets become immediates
// (no runtime division/branch), per-kstep VALU ~4 (B pointer bump only),
// and the straight-line inner bodies give the scheduler a wide hoist window.
template<int KW, int CX, int TS, int NS, int XS>
__device__ __forceinline__ void lstm_body(
    unsigned short* __restrict__ smem,
    const float* __restrict__ xin, long xbstride,
    const float* __restrict__ hin,
    const unsigned short* __restrict__ Bg,
    const float* __restrict__ bias,
    float* __restrict__ c_buf,
    float* __restrict__ h_out,
    float* __restrict__ y_out, long ybstride,
    int b)
{
    constexpr int PAD = KW / 2;
    constexpr int NP  = TS * TS;
    constexpr int CHX = CX / 8;
    constexpr int CST = NP * 8;              // chunk stride (ushorts)
    constexpr int XPLANE = CHX * CST;
    constexpr int HPLANE = 8 * CST;

    unsigned short* sxh = smem;
    unsigned short* sxl = sxh + XPLANE;
    unsigned short* shh = sxl + XPLANE;
    unsigned short* shl = shh + HPLANE;

    const int tid  = threadIdx.x;
    const int lane = tid & 63, wid = tid >> 6;
    const int ty0 = blockIdx.y * 8, tx0 = blockIdx.x * 8;

    // B fragment stream: wave w owns nfrags {2w, 2w+1} = columns [32w, 32w+32)
    const unsigned short* bq = Bg + (2 * wid) * 512 + lane * 8;

    stage_split<CX, TS, PAD, CST>(xin + (long)b * xbstride, sxh, sxl, ty0, tx0, tid);
    stage_split<64, TS, PAD, CST>(hin + (long)b * 4096 * 64, shh, shl, ty0, tx0, tid);
    __syncthreads();

    f32x4 acc[4][2];
#pragma unroll
    for (int mf = 0; mf < 4; ++mf)
#pragma unroll
        for (int nf = 0; nf < 2; ++nf)
#pragma unroll
            for (int q = 0; q < 4; ++q) acc[mf][nf][q] = 0.0f;

    // thread-const A offsets (ushort units). pixel p = mf*16 + (lane&15)
    const int pb  = lane & 15;
    const int kq  = (lane >> 4) * CST;
    const int av0 = (((pb      >> 3) * TS) + (pb      & 7)) * 8 + kq;
    const int av1 = ((((pb+16) >> 3) * TS) + ((pb+16) & 7)) * 8 + kq;
    const int av2 = ((((pb+32) >> 3) * TS) + ((pb+32) & 7)) * 8 + kq;
    const int av3 = ((((pb+48) >> 3) * TS) + ((pb+48) & 7)) * 8 + kq;

    // one k-step: B from L2 (4x16B), A from LDS (8x16B, immediate offsets),
    // 24 MFMA in 3 passes (ah*bh, al*bh, ah*bl), 8 independent acc chains.
#define KSTEP(PH, PL, SO)                                                 \
    {                                                                     \
        s16x8 Bh0 = *(const s16x8*)(bq);                                  \
        s16x8 Bh1 = *(const s16x8*)(bq + 512);                            \
        s16x8 Bl0 = *(const s16x8*)(bq + 8192);                           \
        s16x8 Bl1 = *(const s16x8*)(bq + 8192 + 512);                     \
        s16x8 A0h = *(const s16x8*)((PH) + (SO) + av0);                   \
        s16x8 A1h = *(const s16x8*)((PH) + (SO) + av1);                   \
        s16x8 A2h = *(const s16x8*)((PH) + (SO) + av2);                   \
        s16x8 A3h = *(const s16x8*)((PH) + (SO) + av3);                   \
        s16x8 A0l = *(const s16x8*)((PL) + (SO) + av0);                   \
        s16x8 A1l = *(const s16x8*)((PL) + (SO) + av1);                   \
        s16x8 A2l = *(const s16x8*)((PL) + (SO) + av2);                   \
        s16x8 A3l = *(const s16x8*)((PL) + (SO) + av3);                   \
        __builtin_amdgcn_s_setprio(1);                                    \
        acc[0][0] = MFMA16(A0h, Bh0, acc[0][0]);                          \
        acc[0][1] = MFMA16(A0h, Bh1, acc[0][1]);                          \
        acc[1][0] = MFMA16(A1h, Bh0, acc[1][0]);                          \
        acc[1][1] = MFMA16(A1h, Bh1, acc[1][1]);                          \
        acc[2][0] = MFMA16(A2h, Bh0, acc[2][0]);                          \
        acc[2][1] = MFMA16(A2h, Bh1, acc[2][1]);                          \
        acc[3][0] = MFMA16(A3h, Bh0, acc[3][0]);                          \
        acc[3][1] = MFMA16(A3h, Bh1, acc[3][1]);                          \
        acc[0][0] = MFMA16(A0l, Bh0, acc[0][0]);                          \
        acc[0][1] = MFMA16(A0l, Bh1, acc[0][1]);                          \
        acc[1][0] = MFMA16(A1l, Bh0, acc[1][0]);                          \
        acc[1][1] = MFMA16(A1l, Bh1, acc[1][1]);                          \
        acc[2][0] = MFMA16(A2l, Bh0, acc[2][0]);                          \
        acc[2][1] = MFMA16(A2l, Bh1, acc[2][1]);                          \
        acc[3][0] = MFMA16(A3l, Bh0, acc[3][0]);                          \
        acc[3][1] = MFMA16(A3l, Bh1, acc[3][1]);                          \
        acc[0][0] = MFMA16(A0h, Bl0, acc[0][0]);                          \
        acc[0][1] = MFMA16(A0h, Bl1, acc[0][1]);                          \
        acc[1][0] = MFMA16(A1h, Bl0, acc[1][0]);                          \
        acc[1][1] = MFMA16(A1h, Bl1, acc[1][1]);                          \
        acc[2][0] = MFMA16(A2h, Bl0, acc[2][0]);                          \
        acc[2][1] = MFMA16(A2h, Bl1, acc[2][1]);                          \
        acc[3][0] = MFMA16(A3h, Bl0, acc[3][0]);                          \
        acc[3][1] = MFMA16(A3h, Bl1, acc[3][1]);                          \
        __builtin_amdgcn_s_setprio(0);                                    \
        bq += 16384;                                                      \
    }

    // ---- x-phase (k-step order matches prep_w: ks = tap [CX=32] or
    //      ks = 2*tap + c2 [CX=64], tap = kh*KW + kw) ----
    if (CX == 32) {
#pragma unroll 1
        for (int kh = 0; kh < KW; ++kh) {
#pragma unroll
            for (int kw = 0; kw < KW; ++kw) {
                KSTEP(sxh, sxl, (kh * TS + kw) * 8);
            }
        }
    } else {
#pragma unroll 1
        for (int kh = 0; kh < KW; ++kh) {
#pragma unroll
            for (int kw = 0; kw < KW; ++kw) {
#pragma unroll
                for (int c2 = 0; c2 < 2; ++c2) {
                    KSTEP(sxh, sxl, c2 * 4 * CST + (kh * TS + kw) * 8);
                }
            }
        }
    }
    // ---- h-phase (C=64): ks-XS = 2*tap + c2 ----
#pragma unroll 1
    for (int kh = 0; kh < KW; ++kh) {
#pragma unroll
        for (int kw = 0; kw < KW; ++kw) {
#pragma unroll
            for (int c2 = 0; c2 < 2; ++c2) {
                KSTEP(shh, shl, c2 * 4 * CST + (kh * TS + kw) * 8);
            }
        }
    }

    // ---- z exchange (2 rounds of 32 pixels, row stride 260) + gates ----
    __syncthreads();
    float* zl = (float*)smem;  // 32 x 260 f32 = 33.3 KB overlay
    const int f = tid & 63;
    const float bi = bias[f], bfr = bias[64 + f], bg = bias[128 + f], bo = bias[192 + f];

#define ZROUND(RR)                                                            \
    {                                                                         \
        _Pragma("unroll")                                                     \
        for (int mi = 0; mi < 2; ++mi)                                        \
        {                                                                     \
            _Pragma("unroll")                                                 \
            for (int nf = 0; nf < 2; ++nf)                                    \
            {                                                                 \
                _Pragma("unroll")                                             \
                for (int q = 0; q < 4; ++q) {                                 \
                    int pl_ = mi * 16 + (lane >> 4) * 4 + q;                  \
                    int c   = wid * 32 + nf * 16 + (lane & 15);               \
                    zl[pl_ * 260 + (c & 63) * 4 + (c >> 6)] =                 \
                        acc[2 * (RR) + mi][nf][q];                            \
                }                                                             \
            }                                                                 \
        }                                                                     \
        __syncthreads();                                                      \
        _Pragma("unroll")                                                     \
        for (int j = 0; j < 4; ++j) {                                         \
            int pl_ = (tid >> 6) + j * 8;                                     \
            int p   = (RR) * 32 + pl_;                                        \
            f32x4 z4 = *(const f32x4*)(zl + pl_ * 260 + f * 4);               \
            float zi = z4[0] + bi, zf = z4[1] + bfr;                          \
            float zg = z4[2] + bg, zo = z4[3] + bo;                           \
            int y = ty0 + (p >> 3), x = tx0 + (p & 7);                        \
            long o = ((long)((b * 64 + y) * 64 + x)) * 64 + f;                \
            float cv = c_buf[o];                                              \
            float cn = hsig(zf) * cv + hsig(zi) * tanhf(zg);                  \
            c_buf[o] = cn;                                                    \
            float hn = hsig(zo) * tanhf(cn);                                  \
            h_out[o] = hn;                                                    \
            y_out[(long)b * ybstride + ((long)(y * 64 + x)) * 64 + f] =       \
                fmaxf(hn, 0.0f);                                              \
        }                                                                     \
        __syncthreads();                                                      \
    }

    ZROUND(0)
    ZROUND(1)

#undef KSTEP
#undef ZROUND
}

// ---- fused dual-layer launch: z<4 -> layer1 step t, z>=4 -> layer2 step t-1 ----
// (512,2): no forced register cap (r11: capping to 4 waves/EU spills ~100MB
// scratch; r8-r10: body needs >128 total regs so 1 block/CU is the operating
// point). The fusion's win is launch merging (16 -> 9 dispatches).
__global__ __launch_bounds__(512, 2)
void lstm_fused(
    const float* __restrict__ x1, const float* __restrict__ h1in,
    const unsigned short* __restrict__ B1g, const float* __restrict__ bias1,
    float* __restrict__ c1, float* __restrict__ h1out, float* __restrict__ y1out,
    const float* __restrict__ x2, const float* __restrict__ h2in,
    const unsigned short* __restrict__ B2g, const float* __restrict__ bias2,
    float* __restrict__ c2, float* __restrict__ h2out, float* __restrict__ y2out,
    int mode)
{
    __shared__ __align__(16) unsigned short smem[27648];  // 55296 B
    const int z = blockIdx.z;
    const int b = z & 3;
    const bool doL2 = (mode == 1) || (z >= 4);
    if (!doL2) {
        lstm_body<5, 32, 12, 75, 25>(smem, x1, (long)8 * 4096 * 32, h1in,
                                     B1g, bias1, c1, h1out,
                                     y1out, (long)8 * 4096 * 64, b);
    } else {
        lstm_body<3, 64, 10, 36, 18>(smem, x2, (long)8 * 4096 * 64, h2in,
                                     B2g, bias2, c2, h2out,
                                     y2out, (long)8 * 4096 * 64, b);
    }
}

extern "C" void kernel_launch(void* const* d_in, const int* in_sizes, int n_in,
                              void* d_out, int out_size, void* d_ws, size_t ws_size,
                              hipStream_t stream)
{
    const float* x  = (const float*)d_in[0];
    const float* K1 = (const float*)d_in[1];
    const float* R1 = (const float*)d_in[2];
    const float* b1 = (const float*)d_in[3];
    const float* K2 = (const float*)d_in[4];
    const float* R2 = (const float*)d_in[5];
    const float* b2 = (const float*)d_in[6];
    float* out = (float*)d_out;

    const long HW   = 4096;
    const long SZ_S = HW * 64 * 4;      // 1,048,576 floats per [B,H,W,64]
    const long SZ_Y = SZ_S * 8;

    float* ws  = (float*)d_ws;
    float* y1  = ws;                    // 8,388,608 f32 ([B][T][HW][64])
    float* h1a = y1 + SZ_Y;
    float* h1b = h1a + SZ_S;
    float* h2a = h1b + SZ_S;
    float* h2b = h2a + SZ_S;
    float* c1  = h2b + SZ_S;
    float* c2  = c1 + SZ_S;
    unsigned short* B1 = (unsigned short*)(c2 + SZ_S);   // 75*16384 ushorts
    unsigned short* B2 = B1 + (long)75 * 16384;          // 36*16384 ushorts

    // weight prep
    prep_w<25, 32, 75><<<300, 256, 0, stream>>>(K1, R1, B1);
    prep_w<9,  64, 36><<<144, 256, 0, stream>>>(K2, R2, B2);

    hipMemsetAsync(h1a, 0, (size_t)SZ_S * sizeof(float), stream);
    hipMemsetAsync(c1,  0, (size_t)SZ_S * sizeof(float), stream);
    hipMemsetAsync(h2a, 0, (size_t)SZ_S * sizeof(float), stream);
    hipMemsetAsync(c2,  0, (size_t)SZ_S * sizeof(float), stream);

    float* hp1 = h1a; float* hn1 = h1b;
    float* hp2 = h2a; float* hn2 = h2b;

    for (int t = 0; t <= 8; ++t) {
        const int mode = (t == 0) ? 0 : (t == 8) ? 1 : 2;
        const int t1  = (t <= 7) ? t : 7;       // L1 timestep (unused at t=8)
        const int tm1 = (t >= 1) ? t - 1 : 0;   // L2 timestep (unused at t=0)
        dim3 grid(8, 8, mode == 2 ? 8 : 4);
        lstm_fused<<<grid, 512, 0, stream>>>(
            x  + (long)t1 * HW * 32,  hp1, B1, b1, c1, hn1,
            y1 + (long)t1 * HW * 64,
            y1 + (long)tm1 * HW * 64, hp2, B2, b2, c2, hn2,
            out + (long)tm1 * HW * 64,
            mode);
        if (mode != 1) { float* tmp = hp1; hp1 = hn1; hn1 = tmp; }
        if (mode != 0) { float* tmp = hp2; hp2 = hn2; hn2 = tmp; }
    }
}